// Round 3
// baseline (598.744 us; speedup 1.0000x reference)
//
#include <hip/hip_runtime.h>
#include <math.h>

// Problem constants
#define B_   4
#define N_   4096
#define K_   32
#define C_   192
#define CH_  195          // C + 3 (logical GEMM K)
#define KPAD 224          // 7 x 32 ; rows: 0..191=channels, 192..194=dp, 195..223=0
#define PTS  2            // points per block
#define NKT  7            // K-tiles total
#define NKT0 4            // K-tiles in half 0 (octets 0..15)
#define NNT  4            // N-tiles (64 cols / 16)
#define GRID ((B_ * N_) / PTS)   // 8192 blocks, dense dispatch (locality mechanism!)

using half8  = __attribute__((ext_vector_type(8))) _Float16;
using half2v = __attribute__((ext_vector_type(2))) _Float16;
using f32x4  = __attribute__((ext_vector_type(4))) float;

// Module-static device scratch (NOT d_ws — R4 post-mortem: overran ws_size).
__device__ _Float16 g_Wp[C_ * KPAD];                    // 86016 B (rows pre-scaled by BN inv)
__device__ _Float16 g_xT[(size_t)B_ * N_ * C_];         // 6291456 B

// 16-lane max reduction on the VALU via DPP (no DS pipe)
__device__ __forceinline__ float dpp_max16(float v) {
    int s;
    s = __builtin_amdgcn_update_dpp(0, __float_as_int(v), 0xB1,  0xF, 0xF, true); // quad xor1
    v = fmaxf(v, __int_as_float(s));
    s = __builtin_amdgcn_update_dpp(0, __float_as_int(v), 0x4E,  0xF, 0xF, true); // quad xor2
    v = fmaxf(v, __int_as_float(s));
    s = __builtin_amdgcn_update_dpp(0, __float_as_int(v), 0x141, 0xF, 0xF, true); // half-mirror
    v = fmaxf(v, __int_as_float(s));
    s = __builtin_amdgcn_update_dpp(0, __float_as_int(v), 0x140, 0xF, 0xF, true); // row mirror
    v = fmaxf(v, __int_as_float(s));
    return v;
}

// ---- fused prep: blocks 0..511 transpose x -> g_xT ; blocks 512.. convert W ----
// NOTE (R3): g_Wp row order changed — rows 0..191 = channel weights (W cols 3..194),
// rows 192..194 = dp weights (W cols 0..2), rest zero. Matches hb octet order.
__global__ __launch_bounds__(256) void prep(const float* __restrict__ x,
                                            const float* __restrict__ W,
                                            const float* __restrict__ gamma_,
                                            const float* __restrict__ rvar) {
    const int tid = threadIdx.x;
    if (blockIdx.x < 512) {
        __shared__ float s[32][201];
        const int b  = blockIdx.x >> 7;          // 4 batches x 128 tiles
        const int n0 = (blockIdx.x & 127) * 32;
        const int cl = tid >> 3;                 // 0..31 channel-within-iter
        const int n4 = (tid & 7) * 4;            // 0..28, x4 floats
#pragma unroll
        for (int it = 0; it < 6; ++it) {
            const int c = it * 32 + cl;
            const float4 v = *(const float4*)(x + ((size_t)b * C_ + c) * N_ + n0 + n4);
            s[n4 + 0][c] = v.x; s[n4 + 1][c] = v.y; s[n4 + 2][c] = v.z; s[n4 + 3][c] = v.w;
        }
        __syncthreads();
        const int n  = tid >> 3;                 // 0..31
        const int og = tid & 7;                  // octet-group
#pragma unroll
        for (int it = 0; it < 3; ++it) {
            const int oc = it * 8 + og;          // 0..23 channel octet
            half8 v;
#pragma unroll
            for (int jj = 0; jj < 8; ++jj) v[jj] = (_Float16)s[n][oc * 8 + jj];
            *(half8*)(g_xT + ((size_t)b * N_ + n0 + n) * C_ + oc * 8) = v;
        }
    } else {
        const int i = (blockIdx.x - 512) * 256 + tid;
        if (i < C_ * KPAD) {
            const int o = i / KPAD, r = i - o * KPAD;
            const float inv = gamma_[o] * rsqrtf(rvar[o] + 1e-5f);  // BN scale folded into W
            float v = 0.0f;
            if (r < 192)      v = W[o * CH_ + 3 + r];      // channel weights
            else if (r < 195) v = W[o * CH_ + (r - 192)];  // dp weights
            g_Wp[i] = (_Float16)(v * inv);
        }
    }
}

// ---- main fused kernel: one block = 2 points, 256 threads, 8 blocks/CU ----
// R3: K split into two passes over a half-size hb (16 KB) -> LDS ~18.8 KB -> 8 blocks/CU.
__global__ __launch_bounds__(256, 8) void la_mfma(
    const float* __restrict__ p,      // [B,N,3]
    const int*   __restrict__ idx,    // [B,N,K]
    const float* __restrict__ gamma_,
    const float* __restrict__ beta_,
    const float* __restrict__ rmean,
    const float* __restrict__ rvar,
    float* __restrict__ out)          // [B,C,N]
{
    __shared__ _Float16 hb[NKT0 * NNT * 64 * 8];   // 16384 B, B-fragment order (half-K)
    __shared__ float s_bias[C_], s_fr[32], s_out[C_ * PTS];

    const int tid  = threadIdx.x;
    const int lane = tid & 63;
    const int w    = tid >> 6;
    const int l15  = lane & 15;
    const int quad = lane >> 4;

    // XCD swizzle: keep each XCD inside one batch's xT slice (L2-resident)
    const int q  = blockIdx.x & 7;
    const int sI = blockIdx.x >> 3;
    const int L  = q * (GRID / 8) + sI;
    const int bn0 = L * PTS;
    const int b   = bn0 >> 12;
    const int n0  = bn0 & (N_ - 1);

    if (tid < C_) {
        const float inv = gamma_[tid] * rsqrtf(rvar[tid] + 1e-5f);
        s_bias[tid] = beta_[tid] - rmean[tid] * inv;   // scale part lives in g_Wp
    }
    // s_fr[f] = (50 / 2pi) * 500^(-f/32)   (v_sin takes revolutions)
    if (tid < 32) s_fr[tid] = 7.9577471546f * exp2f(-(float)tid * 0.2801808715263400f);
    __syncthreads();

    // ---- Phase B setup (persists in registers across both halves) ----
    const int col = w * 16 + l15;     // n-tile = w
    const int pt  = col >> 5;
    const int k   = col & 31;
    const int gp  = bn0 + pt;
    const int j   = idx[(size_t)gp * K_ + k];
    const float d0 = p[(size_t)(b * N_ + j) * 3 + 0] - p[(size_t)gp * 3 + 0];
    const float d1 = p[(size_t)(b * N_ + j) * 3 + 1] - p[(size_t)gp * 3 + 1];
    const float d2 = p[(size_t)(b * N_ + j) * 3 + 2] - p[(size_t)gp * 3 + 2];
    const _Float16* xh = g_xT + ((size_t)b * N_ + j) * C_;

    // per-thread frequency set is chunk-invariant: f = quad*8 + jj (chunk&3 == quad)
    float sfr[8];
#pragma unroll
    for (int jj = 0; jj < 8; ++jj) sfr[jj] = s_fr[quad * 8 + jj];

    // emit one channel octet (chunk == octet now; dp moved to octet 24)
    auto emit_chunk = [&](int i6) {
        const int chunk = quad + 4 * i6;           // 0..23
        const half8 v = *(const half8*)(xh + chunk * 8);
        const float dd  = (chunk < 8) ? d0 : ((chunk < 16) ? d1 : d2);
        const float off = (chunk & 4) ? 0.25f : 0.0f;   // cos = sin(+1/4 rev)
        half8 hv;
#pragma unroll
        for (int jj = 0; jj < 8; jj += 2) {
            const float pe0 = __builtin_amdgcn_sinf(fmaf(dd, sfr[jj],     off));
            const float pe1 = __builtin_amdgcn_sinf(fmaf(dd, sfr[jj + 1], off));
            const half2v pe2 = __builtin_bit_cast(half2v, __builtin_amdgcn_cvt_pkrtz(pe0, pe1));
            half2v v2; v2[0] = v[jj]; v2[1] = v[jj + 1];
            const half2v r2 = pe2 * v2 + pe2;   // v_pk_fma_f16: pe*(x+1)
            hv[jj] = r2[0]; hv[jj + 1] = r2[1];
        }
        const int kt  = chunk >> 2;                // global K-tile
        const int kq  = chunk & 3;
        const int lkt = (chunk >= 16) ? (kt - NKT0) : kt;   // slot in half-buffer
        *(half8*)(&hb[(size_t)((lkt * NNT + w) * 64 + kq * 16 + l15) * 8]) = hv;
    };

    f32x4 acc[3][4];
#pragma unroll
    for (int i = 0; i < 3; ++i)
#pragma unroll
        for (int t = 0; t < 4; ++t) acc[i][t] = (f32x4)0.0f;

    // ---- half 0: octets 0..15 (K-tiles 0..3) ----
#pragma unroll
    for (int i6 = 0; i6 < 4; ++i6) emit_chunk(i6);
    __syncthreads();

#pragma unroll
    for (int kt = 0; kt < NKT0; ++kt) {
        const int k0 = kt * 32 + quad * 8;
        half8 a[3], bf[4];
#pragma unroll
        for (int i = 0; i < 3; ++i) {
            const int m = (w * 3 + i) * 16 + l15;
            a[i] = *(const half8*)(g_Wp + (size_t)m * KPAD + k0);   // L1/L2-hot
        }
#pragma unroll
        for (int t = 0; t < 4; ++t)
            bf[t] = *(const half8*)(&hb[(size_t)((kt * NNT + t) * 64 + lane) * 8]);
#pragma unroll
        for (int i = 0; i < 3; ++i)
#pragma unroll
            for (int t = 0; t < 4; ++t)
                acc[i][t] = __builtin_amdgcn_mfma_f32_16x16x32_f16(a[i], bf[t], acc[i][t], 0, 0, 0);
    }
    __syncthreads();   // hb reads done before half-1 overwrites

    // ---- half 1: octets 16..23 (K-tiles 4..5) + dp octet 24 + zero octets 25..27 ----
#pragma unroll
    for (int i6 = 4; i6 < 6; ++i6) emit_chunk(i6);
    if (quad == 0) {        // octet 24: dp rows 192..194 + zeros (K-tile 6, slot 2)
        half8 hv0 = (half8)(_Float16)0.0f;
        hv0[0] = (_Float16)d0; hv0[1] = (_Float16)d1; hv0[2] = (_Float16)d2;
        *(half8*)(&hb[(size_t)((2 * NNT + w) * 64 + 0 * 16 + l15) * 8]) = hv0;
    } else {                // octets 25..27: zero rows
        *(half8*)(&hb[(size_t)((2 * NNT + w) * 64 + quad * 16 + l15) * 8]) = (half8)(_Float16)0.0f;
    }
    __syncthreads();

#pragma unroll
    for (int kt = NKT0; kt < NKT; ++kt) {
        const int k0 = kt * 32 + quad * 8;
        half8 a[3], bf[4];
#pragma unroll
        for (int i = 0; i < 3; ++i) {
            const int m = (w * 3 + i) * 16 + l15;
            a[i] = *(const half8*)(g_Wp + (size_t)m * KPAD + k0);
        }
#pragma unroll
        for (int t = 0; t < 4; ++t)
            bf[t] = *(const half8*)(&hb[(size_t)(((kt - NKT0) * NNT + t) * 64 + lane) * 8]);
#pragma unroll
        for (int i = 0; i < 3; ++i)
#pragma unroll
            for (int t = 0; t < 4; ++t)
                acc[i][t] = __builtin_amdgcn_mfma_f32_16x16x32_f16(a[i], bf[t], acc[i][t], 0, 0, 0);
    }

    // ---- Epilogue: max over 32 neighbors (DPP) -> +bias -> ReLU, staged via s_out ----
    // (R2 post-mortem: direct scattered stores broke L2 write-merging -> 6x HBM writes.)
    // C/D layout: col = lane&15, row = quad*4 + reg ; bias is k-invariant -> after max
#pragma unroll
    for (int i = 0; i < 3; ++i) {
        const int mbase = (w * 3 + i) * 16 + quad * 4;
#pragma unroll
        for (int ptc = 0; ptc < PTS; ++ptc) {
            const f32x4 va = acc[i][2 * ptc];
            const f32x4 vb = acc[i][2 * ptc + 1];
#pragma unroll
            for (int r = 0; r < 4; ++r) {
                float v = fmaxf(va[r], vb[r]);
                v = dpp_max16(v);
                if (l15 == 0) {
                    const int m = mbase + r;
                    s_out[m * PTS + ptc] = fmaxf(v + s_bias[m], 0.0f);
                }
            }
        }
    }
    __syncthreads();

    if (tid < C_) {
        const float2 o2 = *(const float2*)(&s_out[tid * PTS]);
        *(float2*)(&out[((size_t)b * C_ + tid) * N_ + n0]) = o2;
    }
}

extern "C" void kernel_launch(void* const* d_in, const int* in_sizes, int n_in,
                              void* d_out, int out_size, void* d_ws, size_t ws_size,
                              hipStream_t stream) {
    (void)in_sizes; (void)n_in; (void)out_size; (void)d_ws; (void)ws_size;
    const float* p      = (const float*)d_in[0];
    const float* x      = (const float*)d_in[1];
    const int*   idx    = (const int*)d_in[2];
    const float* W      = (const float*)d_in[3];
    const float* gamma_ = (const float*)d_in[4];
    const float* beta_  = (const float*)d_in[5];
    const float* rmean  = (const float*)d_in[6];
    const float* rvar   = (const float*)d_in[7];
    float* out = (float*)d_out;

    prep<<<512 + (C_ * KPAD + 255) / 256, 256, 0, stream>>>(x, W, gamma_, rvar);
    la_mfma<<<GRID, 256, 0, stream>>>(p, idx, gamma_, beta_, rmean, rvar, out);
}

// Round 4
// 162.832 us; speedup vs baseline: 3.6771x; 3.6771x over previous
//
#include <hip/hip_runtime.h>
#include <math.h>

// Problem constants
#define B_   4
#define N_   4096
#define K_   32
#define C_   192
#define CH_  195          // C + 3 (logical GEMM K)
#define KPAD 224          // 7 x 32 ; g_Wp cols: 0..191=channels, 192..194=dp, 195..223=0
#define PTS  2            // points per block
#define NKT  7            // K-tiles
#define NNT  4            // N-tiles (64 cols / 16)
#define GRID ((B_ * N_) / PTS)   // 8192 blocks, dense dispatch (locality mechanism!)

using half8  = __attribute__((ext_vector_type(8))) _Float16;
using half2v = __attribute__((ext_vector_type(2))) _Float16;
using f32x4  = __attribute__((ext_vector_type(4))) float;

// Module-static device scratch (NOT d_ws — R4 post-mortem: overran ws_size).
__device__ _Float16 g_Wp[C_ * KPAD];                    // 86016 B (rows pre-scaled by BN inv)
__device__ _Float16 g_xT[(size_t)B_ * N_ * C_];         // 6291456 B

// ---- fused prep: blocks 0..511 transpose x -> g_xT ; blocks 512.. convert W ----
// g_Wp row o, col r: r<192 -> W[o][3+r] (channels), 192..194 -> W[o][r-192] (dp), else 0.
__global__ __launch_bounds__(256) void prep(const float* __restrict__ x,
                                            const float* __restrict__ W,
                                            const float* __restrict__ gamma_,
                                            const float* __restrict__ rvar) {
    const int tid = threadIdx.x;
    if (blockIdx.x < 512) {
        __shared__ float s[32][201];
        const int b  = blockIdx.x >> 7;          // 4 batches x 128 tiles
        const int n0 = (blockIdx.x & 127) * 32;
        const int cl = tid >> 3;                 // 0..31 channel-within-iter
        const int n4 = (tid & 7) * 4;            // 0..28, x4 floats
#pragma unroll
        for (int it = 0; it < 6; ++it) {
            const int c = it * 32 + cl;
            const float4 v = *(const float4*)(x + ((size_t)b * C_ + c) * N_ + n0 + n4);
            s[n4 + 0][c] = v.x; s[n4 + 1][c] = v.y; s[n4 + 2][c] = v.z; s[n4 + 3][c] = v.w;
        }
        __syncthreads();
        const int n  = tid >> 3;                 // 0..31
        const int og = tid & 7;                  // octet-group
#pragma unroll
        for (int it = 0; it < 3; ++it) {
            const int oc = it * 8 + og;          // 0..23 channel octet
            half8 v;
#pragma unroll
            for (int jj = 0; jj < 8; ++jj) v[jj] = (_Float16)s[n][oc * 8 + jj];
            *(half8*)(g_xT + ((size_t)b * N_ + n0 + n) * C_ + oc * 8) = v;
        }
    } else {
        const int i = (blockIdx.x - 512) * 256 + tid;
        if (i < C_ * KPAD) {
            const int o = i / KPAD, r = i - o * KPAD;
            const float inv = gamma_[o] * rsqrtf(rvar[o] + 1e-5f);  // BN scale folded into W
            float v = 0.0f;
            if (r < 192)      v = W[o * CH_ + 3 + r];      // channel weights
            else if (r < 195) v = W[o * CH_ + (r - 192)];  // dp weights
            g_Wp[i] = (_Float16)(v * inv);
        }
    }
}

// ---- main fused kernel: one block = 2 points, 256 threads, 5 blocks/CU ----
// R4: TRANSPOSED MFMA (operand swap; identical loads) -> neighbors on regs/quads,
// channels on lanes -> epilogue max is mostly in-register (264 -> ~80 VALU inst/wave).
__global__ __launch_bounds__(256, 5) void la_mfma(
    const float* __restrict__ p,      // [B,N,3]
    const int*   __restrict__ idx,    // [B,N,K]
    const float* __restrict__ gamma_,
    const float* __restrict__ beta_,
    const float* __restrict__ rmean,
    const float* __restrict__ rvar,
    float* __restrict__ out)          // [B,C,N]
{
    __shared__ _Float16 hb[NKT * NNT * 64 * 8];   // 28672 B, B-fragment order
    __shared__ float s_bias[C_], s_fr[32], s_out[C_ * PTS];

    const int tid  = threadIdx.x;
    const int lane = tid & 63;
    const int w    = tid >> 6;
    const int l15  = lane & 15;
    const int quad = lane >> 4;

    // XCD swizzle: keep each XCD inside one batch's xT slice (L2-resident)
    const int q  = blockIdx.x & 7;
    const int sI = blockIdx.x >> 3;
    const int L  = q * (GRID / 8) + sI;
    const int bn0 = L * PTS;
    const int b   = bn0 >> 12;
    const int n0  = bn0 & (N_ - 1);

    if (tid < C_) {
        const float inv = gamma_[tid] * rsqrtf(rvar[tid] + 1e-5f);
        s_bias[tid] = beta_[tid] - rmean[tid] * inv;   // scale part lives in g_Wp
    }
    // s_fr[f] = (50 / 2pi) * 500^(-f/32)   (v_sin takes revolutions)
    if (tid < 32) s_fr[tid] = 7.9577471546f * exp2f(-(float)tid * 0.2801808715263400f);
    __syncthreads();

    // ---- Phase B: conflict-free frag-order build of h tile ----
    {
        const int col = w * 16 + l15;     // n-tile = w
        const int pt  = col >> 5;
        const int k   = col & 31;
        const int gp  = bn0 + pt;
        const int j   = idx[(size_t)gp * K_ + k];
        const float d0 = p[(size_t)(b * N_ + j) * 3 + 0] - p[(size_t)gp * 3 + 0];
        const float d1 = p[(size_t)(b * N_ + j) * 3 + 1] - p[(size_t)gp * 3 + 1];
        const float d2 = p[(size_t)(b * N_ + j) * 3 + 2] - p[(size_t)gp * 3 + 2];
        const _Float16* xh = g_xT + ((size_t)b * N_ + j) * C_;

        // hoist ALL 6 gather loads: 6 independent L2 latencies in flight (R4)
        half8 v6[6];
#pragma unroll
        for (int i6 = 0; i6 < 6; ++i6)
            v6[i6] = *(const half8*)(xh + (quad + 4 * i6) * 8);

        // per-thread frequency set is chunk-invariant: f = quad*8 + jj (chunk%4 == quad)
        float sfr[8];
#pragma unroll
        for (int jj = 0; jj < 8; ++jj) sfr[jj] = s_fr[quad * 8 + jj];

#pragma unroll
        for (int i6 = 0; i6 < 6; ++i6) {
            const int chunk = quad + 4 * i6;           // channel octet 0..23
            const half8 v = v6[i6];
            const float dd  = (chunk < 8) ? d0 : ((chunk < 16) ? d1 : d2);
            const float off = (chunk & 4) ? 0.25f : 0.0f;   // cos = sin(+1/4 rev)
            half8 hv;
#pragma unroll
            for (int jj = 0; jj < 8; jj += 2) {
                const float pe0 = __builtin_amdgcn_sinf(fmaf(dd, sfr[jj],     off));
                const float pe1 = __builtin_amdgcn_sinf(fmaf(dd, sfr[jj + 1], off));
                const half2v pe2 = __builtin_bit_cast(half2v, __builtin_amdgcn_cvt_pkrtz(pe0, pe1));
                half2v v2; v2[0] = v[jj]; v2[1] = v[jj + 1];
                const half2v r2 = pe2 * v2 + pe2;   // v_pk_fma_f16: pe*(x+1)
                hv[jj] = r2[0]; hv[jj + 1] = r2[1];
            }
            const int kt = chunk >> 2;              // K-tile 0..5
            *(half8*)(&hb[(size_t)((kt * NNT + w) * 64 + quad * 16 + l15) * 8]) = hv;
        }
        if (quad == 0) {        // octet 24: dp rows 192..194 + zeros (K-tile 6, slot 0)
            half8 hv0 = (half8)(_Float16)0.0f;
            hv0[0] = (_Float16)d0; hv0[1] = (_Float16)d1; hv0[2] = (_Float16)d2;
            *(half8*)(&hb[(size_t)((6 * NNT + w) * 64 + 0 * 16 + l15) * 8]) = hv0;
        } else {                // octets 25..27: zero rows 200..223
            *(half8*)(&hb[(size_t)((6 * NNT + w) * 64 + quad * 16 + l15) * 8]) = (half8)(_Float16)0.0f;
        }
    }
    __syncthreads();

    // ---- Phase C: transposed MFMA GEMM  y'[64 x 192] = h^T * Wp^T ----
    // Identical loads to the untransposed form; only the operand roles swap.
    f32x4 acc[3][4];
#pragma unroll
    for (int i = 0; i < 3; ++i)
#pragma unroll
        for (int t = 0; t < 4; ++t) acc[i][t] = (f32x4)0.0f;

#pragma unroll
    for (int kt = 0; kt < NKT; ++kt) {
        const int k0 = kt * 32 + quad * 8;
        half8 a[3], bf[4];
#pragma unroll
        for (int i = 0; i < 3; ++i) {
            const int m = (w * 3 + i) * 16 + l15;
            a[i] = *(const half8*)(g_Wp + (size_t)m * KPAD + k0);   // L1/L2-hot
        }
#pragma unroll
        for (int t = 0; t < 4; ++t)
            bf[t] = *(const half8*)(&hb[(size_t)((kt * NNT + t) * 64 + lane) * 8]);
#pragma unroll
        for (int i = 0; i < 3; ++i)
#pragma unroll
            for (int t = 0; t < 4; ++t)   // SWAPPED: A=h-frag, B=W-frag -> D = (W.h)^T
                acc[i][t] = __builtin_amdgcn_mfma_f32_16x16x32_f16(bf[t], a[i], acc[i][t], 0, 0, 0);
    }

    // ---- Epilogue (R4): acc[i][t] = D'[neighbor row = t*16+quad*4+r][out-ch = (w*3+i)*16+l15]
    // max over 32 neighbors of point pt = tiles {2pt,2pt+1}: 8 in-lane values ->
    // 7 fmax + cross-quad butterfly (xor16, xor32). 16 channels reduced at once.
#pragma unroll
    for (int i = 0; i < 3; ++i) {
        const int m = (w * 3 + i) * 16 + l15;
        float vv[PTS];
#pragma unroll
        for (int ptc = 0; ptc < PTS; ++ptc) {
            const f32x4 va = acc[i][2 * ptc];
            const f32x4 vb = acc[i][2 * ptc + 1];
            float v = fmaxf(fmaxf(fmaxf(va[0], va[1]), fmaxf(va[2], va[3])),
                            fmaxf(fmaxf(vb[0], vb[1]), fmaxf(vb[2], vb[3])));
            v = fmaxf(v, __shfl_xor(v, 16, 64));
            v = fmaxf(v, __shfl_xor(v, 32, 64));
            vv[ptc] = v;
        }
        if (quad == 0) {
            const float bias = s_bias[m];
            float2 o2;
            o2.x = fmaxf(vv[0] + bias, 0.0f);
            o2.y = fmaxf(vv[1] + bias, 0.0f);
            *(float2*)(&s_out[m * PTS]) = o2;
        }
    }
    __syncthreads();

    // staged store (R2 post-mortem: direct scattered 8B stores broke L2 write-merge)
    if (tid < C_) {
        const float2 o2 = *(const float2*)(&s_out[tid * PTS]);
        *(float2*)(&out[((size_t)b * C_ + tid) * N_ + n0]) = o2;
    }
}

extern "C" void kernel_launch(void* const* d_in, const int* in_sizes, int n_in,
                              void* d_out, int out_size, void* d_ws, size_t ws_size,
                              hipStream_t stream) {
    (void)in_sizes; (void)n_in; (void)out_size; (void)d_ws; (void)ws_size;
    const float* p      = (const float*)d_in[0];
    const float* x      = (const float*)d_in[1];
    const int*   idx    = (const int*)d_in[2];
    const float* W      = (const float*)d_in[3];
    const float* gamma_ = (const float*)d_in[4];
    const float* beta_  = (const float*)d_in[5];
    const float* rmean  = (const float*)d_in[6];
    const float* rvar   = (const float*)d_in[7];
    float* out = (float*)d_out;

    prep<<<512 + (C_ * KPAD + 255) / 256, 256, 0, stream>>>(x, W, gamma_, rvar);
    la_mfma<<<GRID, 256, 0, stream>>>(p, idx, gamma_, beta_, rmean, rvar, out);
}